// Round 1
// 838.590 us; speedup vs baseline: 1.0286x; 1.0286x over previous
//
#include <hip/hip_runtime.h>
#include <hip/hip_bf16.h>

typedef _Float16 half2_t __attribute__((ext_vector_type(2)));
typedef _Float16 half4_t __attribute__((ext_vector_type(4)));
typedef _Float16 half8_t __attribute__((ext_vector_type(8)));
typedef float    f32x4   __attribute__((ext_vector_type(4)));

static __device__ __forceinline__ half2_t pk2(float a, float b) {
#if __has_builtin(__builtin_amdgcn_cvt_pkrtz)
    auto r = __builtin_amdgcn_cvt_pkrtz(a, b);
    half2_t h; h[0] = (_Float16)r[0]; h[1] = (_Float16)r[1]; return h;
#else
    half2_t h; h[0] = (_Float16)a; h[1] = (_Float16)b; return h;
#endif
}

#if __has_builtin(__builtin_amdgcn_fdot2)
#define FDOT2(a, b, c) __builtin_amdgcn_fdot2((a), (b), (c), false)
#else
#define FDOT2(a, b, c) fmaf((float)(a)[0], (float)(b)[0], fmaf((float)(a)[1], (float)(b)[1], (c)))
#endif

// ---------------- cast + transpose: Wk|Wq|Wv fp32 [1024][64] -> wT fp16 [192][1024] ----------------
__global__ __launch_bounds__(256) void cast_wT(const float* __restrict__ Wk,
                                               const float* __restrict__ Wq,
                                               const float* __restrict__ Wv,
                                               _Float16* __restrict__ wT) {
    int idx = blockIdx.x * 256 + threadIdx.x;       // 192*1024
    int c = idx & 1023, n = idx >> 10;
    float v;
    if (n < 64)       v = Wk[c * 64 + n];
    else if (n < 128) v = Wq[c * 64 + (n - 64)];
    else              v = Wv[c * 64 + (n - 128)];
    wT[idx] = (_Float16)v;
}

// ---------------- fused: per-batch QKV GEMM (128x192, K=1024) + causal attention ----------------
// One block = one batch b. GEMM fragments are scattered straight to the attention's
// fp16 LDS layout; qkv never touches HBM.
#define LDA 40
#define LDB 40

// LDS layout (bytes), GEMM region aliased under attn region:
//  GEMM:  As [128*40] halfs @ 0      (10240 B)
//         Bt [192*40] halfs @ 10240  (15360 B)   -> ends 25600
//  ATTN:  ks [128*72] halfs @ 0      (18432 B)
//         qs [128*72] halfs @ 18432  (18432 B)
//         vT [64*136] halfs @ 36864  (17408 B)
//         ps [4*128]  halfs @ 54272  ( 1024 B)   -> total 55296
__global__ __launch_bounds__(256, 2) void fused_head(const float* __restrict__ x,
                                                     const _Float16* __restrict__ wT,  // [192][1024]
                                                     float* __restrict__ out) {
    __shared__ __align__(16) char smem[55296];
    _Float16* As = (_Float16*)smem;
    _Float16* Bt = (_Float16*)(smem + 10240);
    _Float16* ks = (_Float16*)smem;
    _Float16* qs = (_Float16*)(smem + 18432);
    _Float16* vT = (_Float16*)(smem + 36864);
    _Float16* ps = (_Float16*)(smem + 54272);

    const int tid  = threadIdx.x;
    const int b    = blockIdx.x;
    const int m0   = b * 128;
    const int wave = tid >> 6;
    const int lane = tid & 63;
    const int wm   = wave * 32;
    const int lrow = lane & 15;
    const int lq   = lane >> 4;

    f32x4 acc[2][12] = {};

    // staging maps
    const int arow = tid >> 3;          // 0..31 (+p*32)
    const int acol = (tid & 7) * 4;     // float/half k-offset, 0..28
    const int brow = tid >> 2;          // 0..63 (+p*64)
    const int bcol = (tid & 3) * 8;     // half k-offset, 0..24

    const float*    xg = x  + (size_t)(m0 + arow) * 1024 + acol;
    const _Float16* wg = wT + (size_t)brow * 1024 + bcol;

    for (int kb = 0; kb < 1024; kb += 32) {
        // ---- stage A: 128 rows x 32 halfs ----
        #pragma unroll
        for (int p = 0; p < 4; ++p) {
            float4 a = *(const float4*)(xg + (size_t)p * 32 * 1024 + kb);
            half2_t h0 = pk2(a.x, a.y), h1 = pk2(a.z, a.w);
            half4_t hv = {h0[0], h0[1], h1[0], h1[1]};
            *(half4_t*)&As[(arow + p * 32) * LDA + acol] = hv;
        }
        // ---- stage B: 192 rows x 32 halfs (straight copy, wT already transposed) ----
        #pragma unroll
        for (int p = 0; p < 3; ++p) {
            half8_t bv = *(const half8_t*)(wg + (size_t)p * 64 * 1024 + kb);
            *(half8_t*)&Bt[(brow + p * 64) * LDB + bcol] = bv;
        }
        __syncthreads();

        half8_t aF0 = *(const half8_t*)&As[(wm + lrow) * LDA + lq * 8];
        half8_t aF1 = *(const half8_t*)&As[(wm + 16 + lrow) * LDA + lq * 8];
        #pragma unroll
        for (int nt = 0; nt < 12; ++nt) {
            half8_t bF = *(const half8_t*)&Bt[(nt * 16 + lrow) * LDB + lq * 8];
            acc[0][nt] = __builtin_amdgcn_mfma_f32_16x16x32_f16(aF0, bF, acc[0][nt], 0, 0, 0);
            acc[1][nt] = __builtin_amdgcn_mfma_f32_16x16x32_f16(aF1, bF, acc[1][nt], 0, 0, 0);
        }
        __syncthreads();
    }

    // ---- epilogue: scatter fragments straight into the attention LDS layout ----
    // D[row = wm + mt*16 + lq*4 + r][col = nt*16 + lrow]; cols 0..63 = k, 64..127 = q, 128..191 = v
    // (aliases As/Bt — safe: final __syncthreads of the K-loop ordered all GEMM LDS reads before this)
    #pragma unroll
    for (int mt = 0; mt < 2; ++mt)
        #pragma unroll
        for (int nt = 0; nt < 12; ++nt)
            #pragma unroll
            for (int r = 0; r < 4; ++r) {
                int row = wm + mt * 16 + lq * 4 + r;
                int col = nt * 16 + lrow;
                float v = acc[mt][nt][r];
                if (nt < 4)      ks[row * 72 + col] = (_Float16)v;
                else if (nt < 8) qs[row * 72 + (col - 64)] = (_Float16)v;
                else             vT[(col - 128) * 136 + row] = (_Float16)v;
            }
    __syncthreads();

    // ---- causal attention, q/k/v all resident in LDS ----
    const half8_t* k0p = (const half8_t*)&ks[lane * 72];
    const half8_t* k1p = (const half8_t*)&ks[(64 + lane) * 72];
    const half8_t* vp  = (const half8_t*)&vT[lane * 136];
    _Float16* psw = ps + wave * 128;

    for (int rr = 0; rr < 32; ++rr) {
        const int row = rr * 4 + wave;                 // wave-uniform
        const half8_t* qp = (const half8_t*)&qs[row * 72];   // broadcast reads

        // ---- phase 1: scores for keys lane (and 64+lane) ----
        float s0 = 0.f, s1 = -INFINITY;
        {
            float s0a = 0.f, s0b = 0.f;
            if (row >= 64) {
                float s1a = 0.f, s1b = 0.f;
                #pragma unroll
                for (int i = 0; i < 8; ++i) {
                    half8_t qv = qp[i];
                    half2_t q0 = {qv[0], qv[1]}, q1 = {qv[2], qv[3]};
                    half2_t q2 = {qv[4], qv[5]}, q3 = {qv[6], qv[7]};
                    half8_t ka = k0p[i], kb2 = k1p[i];
                    half2_t c0 = {ka[0], ka[1]}, c1 = {ka[2], ka[3]}, c2 = {ka[4], ka[5]}, c3 = {ka[6], ka[7]};
                    half2_t d0 = {kb2[0], kb2[1]}, d1 = {kb2[2], kb2[3]}, d2 = {kb2[4], kb2[5]}, d3 = {kb2[6], kb2[7]};
                    s0a = FDOT2(q0, c0, s0a); s0b = FDOT2(q1, c1, s0b);
                    s0a = FDOT2(q2, c2, s0a); s0b = FDOT2(q3, c3, s0b);
                    s1a = FDOT2(q0, d0, s1a); s1b = FDOT2(q1, d1, s1b);
                    s1a = FDOT2(q2, d2, s1a); s1b = FDOT2(q3, d3, s1b);
                }
                s0 = s0a + s0b;
                s1 = (64 + lane <= row) ? (s1a + s1b) : -INFINITY;
            } else {
                #pragma unroll
                for (int i = 0; i < 8; ++i) {
                    half8_t qv = qp[i];
                    half2_t q0 = {qv[0], qv[1]}, q1 = {qv[2], qv[3]};
                    half2_t q2 = {qv[4], qv[5]}, q3 = {qv[6], qv[7]};
                    half8_t ka = k0p[i];
                    half2_t c0 = {ka[0], ka[1]}, c1 = {ka[2], ka[3]}, c2 = {ka[4], ka[5]}, c3 = {ka[6], ka[7]};
                    s0a = FDOT2(q0, c0, s0a); s0b = FDOT2(q1, c1, s0b);
                    s0a = FDOT2(q2, c2, s0a); s0b = FDOT2(q3, c3, s0b);
                }
                s0 = (lane <= row) ? (s0a + s0b) : -INFINITY;
            }
        }
        // ---- softmax across the wave ----
        float m = fmaxf(s0, s1);
        #pragma unroll
        for (int d = 1; d < 64; d <<= 1) m = fmaxf(m, __shfl_xor(m, d, 64));
        float p0 = __expf(s0 - m), p1 = __expf(s1 - m);
        float l = p0 + p1;
        #pragma unroll
        for (int d = 1; d < 64; d <<= 1) l += __shfl_xor(l, d, 64);
        float inv = 1.f / l;
        psw[lane]      = (_Float16)(p0 * inv);
        psw[64 + lane] = (_Float16)(p1 * inv);

        // ---- phase 2: out[h=lane] = sum_j p[j] * v[j][h] ----
        const int nj = row + 1;
        float o0 = 0.f, o1 = 0.f, o2 = 0.f, o3 = 0.f;
        const int n8 = nj >> 3;
        for (int i = 0; i < n8; ++i) {
            half8_t pv = *(const half8_t*)&psw[i * 8];   // broadcast
            half8_t vv = vp[i];
            half2_t pa = {pv[0], pv[1]}, pb = {pv[2], pv[3]}, pc = {pv[4], pv[5]}, pd = {pv[6], pv[7]};
            half2_t va = {vv[0], vv[1]}, vb = {vv[2], vv[3]}, vc = {vv[4], vv[5]}, vd = {vv[6], vv[7]};
            o0 = FDOT2(pa, va, o0); o1 = FDOT2(pb, vb, o1);
            o2 = FDOT2(pc, vc, o2); o3 = FDOT2(pd, vd, o3);
        }
        for (int j = n8 * 8; j < nj; ++j)
            o0 = fmaf((float)psw[j], (float)vT[lane * 136 + j], o0);

        out[((size_t)m0 + row) * 64 + lane] = (o0 + o1) + (o2 + o3);
    }
}

extern "C" void kernel_launch(void* const* d_in, const int* in_sizes, int n_in,
                              void* d_out, int out_size, void* d_ws, size_t ws_size,
                              hipStream_t stream) {
    const float* x  = (const float*)d_in[0];
    const float* Wk = (const float*)d_in[1];
    const float* Wq = (const float*)d_in[2];
    const float* Wv = (const float*)d_in[3];
    float* out = (float*)d_out;

    _Float16* wT = (_Float16*)d_ws;    // 192*1024*2 = 384 KB

    cast_wT<<<768, 256, 0, stream>>>(Wk, Wq, Wv, wT);
    fused_head<<<1024, 256, 0, stream>>>(x, wT, out);
}